// Round 2
// baseline (103.296 us; speedup 1.0000x reference)
//
#include <hip/hip_runtime.h>
#include <math.h>

// Problem constants (from reference):
//   B = 65536, IN = 128, OUT = 257 (= NUM_GRIDS+1), NUM_BASIS = 5
//   basis(d) = [1, d, d^2, relu(d-0.33)^2, relu(d-0.66)^2]
//   out[b,o] = sum_{i,n} z[b,i] * W[i,o,n] * basis[b,n] + sum_n bias[o,n]*basis[b,n]
//   prob[b]  = lerp(out[b,li], out[b,ui], dist), g = d*256, li=clip(floor(g),0,255)
// KEY: only columns li and ui of `out` are ever needed -> gather, don't GEMM.
//   ui = min(li+1,255) is equivalent to clip(ceil(g),0,255) under the lerp:
//   when ceil==floor, dist==0 so the upper column is multiplied by 0; when
//   li==255 both give ui==255.

constexpr int IN_F = 128;
constexpr int OUTC = 257;
constexpr int NB   = 5;

// One-shot (per call) transpose: wT[o][n][i] <- W[i][o][n]
// Makes the per-row weight gather a contiguous 5120B chunk (float4-friendly).
__global__ __launch_bounds__(256) void transpose_w_kernel(
    const float* __restrict__ w, float* __restrict__ wT)
{
    int idx = blockIdx.x * blockDim.x + threadIdx.x;
    constexpr int TOT = OUTC * NB * IN_F;
    if (idx >= TOT) return;
    int i    = idx & (IN_F - 1);
    int rest = idx >> 7;        // IN_F = 128
    int n    = rest % NB;
    int o    = rest / NB;
    wT[idx] = w[(size_t)i * (OUTC * NB) + o * NB + n];
}

// 16 lanes per row, 4 rows per wave, 256-thread blocks.
// TR=true: w points to wT [o][n][i]; TR=false: w is original [i][o][n].
template<bool TR>
__global__ __launch_bounds__(256) void vcd_main(
    const float* __restrict__ dtr, const float* __restrict__ z,
    const float* __restrict__ w,   const float* __restrict__ bias,
    float* __restrict__ out, int B)
{
    int t   = blockIdx.x * blockDim.x + threadIdx.x;
    int row = t >> 4;
    int s   = threadIdx.x & 15;
    if (row >= B) return;

    float dv = dtr[row];

    // spline basis
    float b1 = dv, b2 = dv * dv;
    float r1 = fmaxf(dv - 0.33f, 0.0f);
    float r2 = fmaxf(dv - 0.66f, 0.0f);
    float b3 = r1 * r1, b4 = r2 * r2;

    // interpolation params (tmp = (d-A)*(B_HI-A) = d here)
    float g     = dv * 256.0f;
    float lower = fminf(fmaxf(floorf(g), 0.0f), 255.0f);
    float dist  = g - lower;
    int   li = (int)lower;
    int   ui = min(li + 1, 255);

    // this lane's 8 features
    const float4* zv = reinterpret_cast<const float4*>(z + (size_t)row * IN_F + s * 8);
    float4 z0 = zv[0], z1 = zv[1];
    float zz[8] = {z0.x, z0.y, z0.z, z0.w, z1.x, z1.y, z1.z, z1.w};

    float accl = 0.0f, accu = 0.0f;

    if constexpr (TR) {
        const float* wl = w + (size_t)li * (NB * IN_F) + s * 8;
        const float* wu = w + (size_t)ui * (NB * IN_F) + s * 8;
        #pragma unroll
        for (int n = 0; n < NB; ++n) {
            float bn = (n == 0) ? 1.0f : (n == 1) ? b1 : (n == 2) ? b2 : (n == 3) ? b3 : b4;
            float4 l0 = reinterpret_cast<const float4*>(wl + n * IN_F)[0];
            float4 l1 = reinterpret_cast<const float4*>(wl + n * IN_F)[1];
            float4 u0 = reinterpret_cast<const float4*>(wu + n * IN_F)[0];
            float4 u1 = reinterpret_cast<const float4*>(wu + n * IN_F)[1];
            float dl = zz[0]*l0.x + zz[1]*l0.y + zz[2]*l0.z + zz[3]*l0.w
                     + zz[4]*l1.x + zz[5]*l1.y + zz[6]*l1.z + zz[7]*l1.w;
            float du = zz[0]*u0.x + zz[1]*u0.y + zz[2]*u0.z + zz[3]*u0.w
                     + zz[4]*u1.x + zz[5]*u1.y + zz[6]*u1.z + zz[7]*u1.w;
            accl = fmaf(bn, dl, accl);
            accu = fmaf(bn, du, accu);
        }
    } else {
        #pragma unroll
        for (int k = 0; k < 8; ++k) {
            const float* wp  = w + (size_t)(s * 8 + k) * (OUTC * NB);
            const float* wlp = wp + li * NB;
            const float* wup = wp + ui * NB;
            float wsl = wlp[0] + b1*wlp[1] + b2*wlp[2] + b3*wlp[3] + b4*wlp[4];
            float wsu = wup[0] + b1*wup[1] + b2*wup[2] + b3*wup[3] + b4*wup[4];
            accl = fmaf(zz[k], wsl, accl);
            accu = fmaf(zz[k], wsu, accu);
        }
    }

    // combine via lerp BEFORE the reduction: prob is linear in (accl, accu),
    // so reduce a single value (4 shuffles instead of 8).
    float comb = fmaf(dist, accu - accl, accl);
    #pragma unroll
    for (int m = 1; m < 16; m <<= 1)
        comb += __shfl_xor(comb, m, 64);

    if (s == 0) {
        const float* blp = bias + li * NB;
        const float* bup = bias + ui * NB;
        float bl = blp[0] + b1*blp[1] + b2*blp[2] + b3*blp[3] + b4*blp[4];
        float bu = bup[0] + b1*bup[1] + b2*bup[2] + b3*bup[3] + b4*bup[4];
        float prob = comb + fmaf(dist, bu - bl, bl);
        bool sup = (dv >= 0.0f) && (dv <= 1.0f);
        out[row] = sup ? prob : 0.0f;
    }
}

extern "C" void kernel_launch(void* const* d_in, const int* in_sizes, int n_in,
                              void* d_out, int out_size, void* d_ws, size_t ws_size,
                              hipStream_t stream) {
    const float* d_d = (const float*)d_in[0];   // d [B]
    const float* d_z = (const float*)d_in[1];   // z [B, 128]
    const float* d_w = (const float*)d_in[2];   // weight [128, 257, 5]
    const float* d_b = (const float*)d_in[3];   // bias [257, 5]
    float* out = (float*)d_out;
    int B = in_sizes[0];

    constexpr size_t WT_BYTES = (size_t)OUTC * NB * IN_F * sizeof(float);
    int main_blocks = (B * 16 + 255) / 256;

    if (ws_size >= WT_BYTES) {
        float* wT = (float*)d_ws;
        constexpr int TOT = OUTC * NB * IN_F;
        transpose_w_kernel<<<(TOT + 255) / 256, 256, 0, stream>>>(d_w, wT);
        vcd_main<true><<<main_blocks, 256, 0, stream>>>(d_d, d_z, wT, d_b, out, B);
    } else {
        vcd_main<false><<<main_blocks, 256, 0, stream>>>(d_d, d_z, d_w, d_b, out, B);
    }
}